// Round 14
// baseline (326.460 us; speedup 1.0000x reference)
//
#include <hip/hip_runtime.h>

typedef __attribute__((ext_vector_type(8))) short short8;
typedef __attribute__((ext_vector_type(4))) float floatx4;

#define T_SIZE 32768
#define OBS    256
#define H      512
#define NC     1024    // scan chunks
#define CHUNK  32      // T_SIZE / NC
#define NGRP   64      // scan2 groups
#define GCH    16      // chunks per group

__device__ __forceinline__ unsigned short f2bf(float f){
    union { float f; unsigned u; } v; v.f = f;
    unsigned u = v.u;
    u += 0x7FFFu + ((u >> 16) & 1u);   // round-to-nearest-even
    return (unsigned short)(u >> 16);
}
__device__ __forceinline__ float bf2f(unsigned short u){
    union { unsigned u; float f; } v; v.u = ((unsigned)u) << 16; return v.f;
}

// async global->LDS, 16B per lane; lds base must be wave-uniform (HW adds lane*16)
#define GLOAD_LDS16(g, l) \
    __builtin_amdgcn_global_load_lds((const __attribute__((address_space(1))) unsigned*)(g), \
                                     (__attribute__((address_space(3))) unsigned*)(l), 16, 0, 0)

// ---- merged prep: cast x -> bf16 (blocks 0..8191), tcast W0 set (8192..10239, K=256),
// ----              tcast W1 set (10240..14335, K=512). K innermost: coalesced writes.
__global__ void prep_kernel(const float* __restrict__ x, unsigned short* __restrict__ xb,
                            const float* __restrict__ A0W0, const float* __restrict__ A0W1,
                            const float* __restrict__ A0W2, const float* __restrict__ A0W3,
                            unsigned short* __restrict__ Wt0,
                            const float* __restrict__ A1W0, const float* __restrict__ A1W1,
                            const float* __restrict__ A1W2, const float* __restrict__ A1W3,
                            unsigned short* __restrict__ Wt1){
    const int b = blockIdx.x;
    const int tid = threadIdx.x;
    if (b < 8192){
        int i = b * 256 + tid;                       // n4 = 2097152 = 8192*256 exactly
        float4 v = ((const float4*)x)[i];
        ushort4 o;
        o.x = f2bf(v.x); o.y = f2bf(v.y); o.z = f2bf(v.z); o.w = f2bf(v.w);
        ((ushort4*)xb)[i] = o;
    } else if (b < 10240){
        const int K = OBS, KH = OBS * H;
        int idx = (b - 8192) * 256 + tid;            // 4*KH = 524288 = 2048*256 exactly
        int s   = idx / KH;
        int rem = idx - s * KH;
        int h = rem >> 8;            // K = 256: k innermost
        int k = rem & 255;
        const float* W = (s == 0) ? A0W0 : (s == 1) ? A0W1 : (s == 2) ? A0W2 : A0W3;
        int bb = h >> 4, hh = h & 15;
        Wt0[(size_t)((bb * 4 + s) * 16 + hh) * K + k] = f2bf(W[(size_t)k * H + h]);
    } else {
        const int K = H, KH = H * H;
        int idx = (b - 10240) * 256 + tid;           // 4*KH = 1048576 = 4096*256 exactly
        int s   = idx / KH;
        int rem = idx - s * KH;
        int h = rem >> 9;            // K = 512: k innermost
        int k = rem & 511;
        const float* W = (s == 0) ? A1W0 : (s == 1) ? A1W1 : (s == 2) ? A1W2 : A1W3;
        int bb = h >> 4, hh = h & 15;
        Wt1[(size_t)((bb * 4 + s) * 16 + hh) * K + k] = f2bf(W[(size_t)k * H + h]);
    }
}

// ---- fused 4-matrix GEMM (ring-3 LDS pipeline) + IN-EPILOGUE LOCAL SCAN ----
// Outputs yl = C*h_local and w = C*prefix (bf16, [T][512]); downstream scan is
// pure elementwise y = yl + w*h_in. Chunk aggregates (Pbuf/Hbuf) as before.
template<int K>
__global__ __launch_bounds__(256, 3) void gemm_layer_kernel(
    const unsigned short* __restrict__ xb,
    const unsigned short* __restrict__ wt,
    const float* __restrict__ A_log,
    unsigned short* __restrict__ ylT, unsigned short* __restrict__ wT,
    float* __restrict__ Pbuf, float* __restrict__ Hbuf)
{
    __shared__ unsigned short SM[3][8192];   // 48 KB

    const int tid  = threadIdx.x;
    const int wave = tid >> 6;
    const int lane = tid & 63;
    const int ml   = lane & 15;
    const int quad = lane >> 4;
    const int wm   = wave & 1;
    const int wn   = wave >> 1;

    const int flat = blockIdx.y * 16 + blockIdx.x;
    const int xcd  = flat & 7;
    const int j    = flat >> 3;
    const int nb   = j & 15;                 // 0..15 : h block of 32
    const int mb   = (j >> 4) * 8 + xcd;     // 0..255 : t tile of 128
    const int m0   = mb * 128;

    const int srow = tid >> 2;
    const int sel  = (((tid & 3) ^ ((tid >> 3) & 3))) * 8;   // staging XOR swizzle
    const int swz  = (ml >> 1) & 3;                          // read-side XOR swizzle

    const unsigned short* pa0 = xb + (size_t)(m0 + srow) * K + sel;
    const unsigned short* pa1 = pa0 + (size_t)64 * K;
    const unsigned short* pb0 = wt + (size_t)(nb * 128 + srow) * K + sel;
    const unsigned short* pb1 = pb0 + (size_t)64 * K;

    const int ldsA0 = (wave * 64 + 0  ) * 8;
    const int ldsA1 = (wave * 64 + 256) * 8;

    const int rbaseA = (wm * 64 + ml) * 32 + (quad ^ swz) * 8;
    const int rbaseB = (wn * 64 + ml) * 32 + (quad ^ swz) * 8;

    floatx4 acc[4][4];
    #pragma unroll
    for (int i = 0; i < 4; i++)
        #pragma unroll
        for (int jj = 0; jj < 4; jj++)
            acc[i][jj] = (floatx4)(0.0f);

    constexpr int NK = K >> 5;   // 8 or 16

#define STAGE(kt_) { const int b_ = (kt_) % 3; const int ko_ = (kt_) * 32; \
        GLOAD_LDS16(pa0 + ko_, &SM[b_][ldsA0]); \
        GLOAD_LDS16(pa1 + ko_, &SM[b_][ldsA1]); \
        GLOAD_LDS16(pb0 + ko_, &SM[b_][4096 + ldsA0]); \
        GLOAD_LDS16(pb1 + ko_, &SM[b_][4096 + ldsA1]); }

    // prologue: stage K-tiles 0,1 (depth-2 prefetch); wait tile 0 only
    STAGE(0); STAGE(1);
    asm volatile("s_waitcnt vmcnt(4)" ::: "memory");
    __builtin_amdgcn_s_barrier();
    __builtin_amdgcn_sched_barrier(0);

    #pragma unroll
    for (int kk = 0; kk < NK; ++kk){
        const int cur = kk % 3;

        if (kk + 2 < NK) STAGE(kk + 2);   // into slot of tile kk-1 (reads done, barrier passed)

        short8 av[4], bv[4];
        #pragma unroll
        for (int i = 0; i < 4; i++)
            av[i] = *(const short8*)(&SM[cur][0] + rbaseA + i * 16 * 32);
        #pragma unroll
        for (int jj = 0; jj < 4; jj++)
            bv[jj] = *(const short8*)(&SM[cur][4096] + rbaseB + jj * 16 * 32);

        __builtin_amdgcn_s_setprio(1);
        #pragma unroll
        for (int i = 0; i < 4; i++)
            #pragma unroll
            for (int jj = 0; jj < 4; jj++)
                acc[i][jj] = __builtin_amdgcn_mfma_f32_16x16x32_bf16(av[i], bv[jj], acc[i][jj], 0, 0, 0);
        __builtin_amdgcn_s_setprio(0);

        if (kk + 1 < NK){
            if (kk + 2 < NK) { asm volatile("s_waitcnt vmcnt(4)" ::: "memory"); }
            else             { asm volatile("s_waitcnt vmcnt(0)" ::: "memory"); }
            __builtin_amdgcn_s_barrier();
            __builtin_amdgcn_sched_barrier(0);
        }
    }
    __syncthreads();   // full drain before epilogue reuses SM

#undef STAGE

    // ---- epilogue pass 1: per-element a/bx/C in regs (fp32); segment aggregates -> segbuf ----
    unsigned short* SMe = &SM[0][0];
    float2* segbuf = (float2*)(SMe + 12288);  // [ch 4][seg 8][col 32] float2 = 8 KB
    const int col = wn * 16 + ml;             // 0..31 h within block
    const int h   = nb * 32 + col;
    const float Aneg = -expf(A_log[h]);

    float va[4][4], vb[4][4], vc[4][4];
    #pragma unroll
    for (int i = 0; i < 4; i++){
        float p = 1.0f, hh = 0.0f;
        #pragma unroll
        for (int r = 0; r < 4; r++){
            float dv = acc[i][3][r];
            float delta = 1.0f / (1.0f + __expf(-dv));
            float a  = __expf(delta * Aneg);
            float bx = acc[i][1][r] * acc[i][0][r];
            va[i][r] = a; vb[i][r] = bx; vc[i][r] = acc[i][2][r];
            hh = fmaf(a, hh, bx);
            p *= a;
        }
        const int ch = wm * 2 + (i >> 1);
        const int s  = (i & 1) * 4 + quad;
        segbuf[(ch * 8 + s) * 32 + col] = make_float2(p, hh);
    }
    __syncthreads();

    // ---- epilogue pass 2: exclusive segment fold; per-element yl=C*h_local, w=C*prefix ----
    #pragma unroll
    for (int i = 0; i < 4; i++){
        const int ch = wm * 2 + (i >> 1);
        const int s  = (i & 1) * 4 + quad;
        float Pexc = 1.0f, Hexc = 0.0f;
        for (int sp = 0; sp < s; sp++){   // <=7 LDS reads, divergent-bounded
            float2 ph = segbuf[(ch * 8 + sp) * 32 + col];
            Hexc = fmaf(ph.x, Hexc, ph.y);
            Pexc *= ph.x;
        }
        float hcur = Hexc, pf = Pexc;
        #pragma unroll
        for (int r = 0; r < 4; r++){
            hcur = fmaf(va[i][r], hcur, vb[i][r]);
            pf  *= va[i][r];
            int trow = wm * 64 + i * 16 + quad * 4 + r;   // C/D: row = quad*4 + reg
            SMe[        trow * 32 + col] = f2bf(vc[i][r] * hcur);
            SMe[4096 +  trow * 32 + col] = f2bf(vc[i][r] * pf);
        }
    }
    if (tid < 128){
        const int ccol = tid & 31, ch = tid >> 5;
        float P = 1.0f, Hc = 0.0f;
        #pragma unroll
        for (int s = 0; s < 8; s++){
            float2 ph = segbuf[(ch * 8 + s) * 32 + ccol];
            Hc = fmaf(ph.x, Hc, ph.y);
            P *= ph.x;
        }
        const int c = mb * 4 + ch;
        Pbuf[(size_t)c * H + nb * 32 + ccol] = P;
        Hbuf[(size_t)c * H + nb * 32 + ccol] = Hc;
    }
    __syncthreads();
    {
        // store yl/w to [T][512]: unit u (16B) -> row u>>2 (0..127), col-part u&3 (8 shorts)
        const short8* s8 = (const short8*)SMe;
        #pragma unroll
        for (int arr = 0; arr < 2; arr++){
            unsigned short* bp = (arr == 0) ? ylT : wT;
            #pragma unroll
            for (int half = 0; half < 2; half++){
                int u = half * 256 + tid;
                int row = u >> 2, part = u & 3;
                *(short8*)(bp + (size_t)(m0 + row) * H + nb * 32 + part * 8) = s8[arr * 512 + u];
            }
        }
    }
}

// ---- scan pass 2a': group aggregates AND per-chunk exclusive intra-group partials ----
__global__ void scan2a_kernel(const float* __restrict__ P, const float* __restrict__ Hc,
                              float* __restrict__ Pg, float* __restrict__ Hg,
                              float* __restrict__ Pexc, float* __restrict__ Hexc){
    const int g  = blockIdx.x;          // 0..63
    const int j4 = threadIdx.x * 4;     // 128 threads
    float4 pc = {1.f,1.f,1.f,1.f}, hc = {0.f,0.f,0.f,0.f};
    #pragma unroll
    for (int i = 0; i < GCH; i++){
        size_t o = (size_t)(g * GCH + i) * H + j4;
        *(float4*)(Pexc + o) = pc;      // exclusive partial BEFORE folding chunk i
        *(float4*)(Hexc + o) = hc;
        float4 P4 = *(const float4*)(P + o);
        float4 H4 = *(const float4*)(Hc + o);
        hc.x = fmaf(P4.x, hc.x, H4.x); pc.x *= P4.x;
        hc.y = fmaf(P4.y, hc.y, H4.y); pc.y *= P4.y;
        hc.z = fmaf(P4.z, hc.z, H4.z); pc.z *= P4.z;
        hc.w = fmaf(P4.w, hc.w, H4.w); pc.w *= P4.w;
    }
    *(float4*)(Pg + (size_t)g * H + j4) = pc;
    *(float4*)(Hg + (size_t)g * H + j4) = hc;
}

// ---- scan pass 2b': per-group parallel group-prefix fold + full chunk prefix Cc ----
// Block g: cg = fold(Pg/Hg[0..g-1]) (same sequential order as before), then
// Cc[c] = fmaf(Pexc[c], cg, Hexc[c]) for its 16 chunks.
__global__ void scan2b_kernel(const float* __restrict__ Pg, const float* __restrict__ Hg,
                              const float* __restrict__ Pexc, const float* __restrict__ Hexc,
                              float* __restrict__ Cc){
    const int g  = blockIdx.x;          // 0..63
    const int j4 = threadIdx.x * 4;     // 128 threads
    float4 cg = {0.f,0.f,0.f,0.f};
    for (int gg = 0; gg < g; ++gg){     // <=63 dependent L2 folds, parallel across blocks
        float4 P4 = *(const float4*)(Pg + (size_t)gg * H + j4);
        float4 H4 = *(const float4*)(Hg + (size_t)gg * H + j4);
        cg.x = fmaf(P4.x, cg.x, H4.x);
        cg.y = fmaf(P4.y, cg.y, H4.y);
        cg.z = fmaf(P4.z, cg.z, H4.z);
        cg.w = fmaf(P4.w, cg.w, H4.w);
    }
    #pragma unroll
    for (int i = 0; i < GCH; i++){
        size_t o = (size_t)(g * GCH + i) * H + j4;
        float4 pe = *(const float4*)(Pexc + o);
        float4 he = *(const float4*)(Hexc + o);
        float4 cc;
        cc.x = fmaf(pe.x, cg.x, he.x);
        cc.y = fmaf(pe.y, cg.y, he.y);
        cc.z = fmaf(pe.z, cg.z, he.z);
        cc.w = fmaf(pe.w, cg.w, he.w);
        *(float4*)(Cc + o) = cc;
    }
}

// ---- scan pass 3 (ELEMENTWISE, zero folds): h_in = Cc[c]; y = yl + w*h_in. ----
__global__ __launch_bounds__(256) void scan3_kernel(
    const unsigned short* __restrict__ ylT, const unsigned short* __restrict__ wT,
    const float* __restrict__ Cc,
    unsigned short* __restrict__ yb){
    const int c    = blockIdx.x;            // chunk 0..NC-1 (wave-uniform)
    const int half = threadIdx.x >> 7;      // rows 0-15 / 16-31 (independent)
    const int j4   = (threadIdx.x & 127) * 4;
    float4 h = *(const float4*)(Cc + (size_t)c * H + j4);
    size_t off = (size_t)(c * CHUNK + half * 16) * H + j4;
    #pragma unroll 8
    for (int i = 0; i < 16; i++){
        ushort4 yl = *(const ushort4*)(ylT + off);
        ushort4 w4 = *(const ushort4*)(wT + off);
        ushort4 o;
        o.x = f2bf(fmaf(bf2f(w4.x), h.x, bf2f(yl.x)));
        o.y = f2bf(fmaf(bf2f(w4.y), h.y, bf2f(yl.y)));
        o.z = f2bf(fmaf(bf2f(w4.z), h.z, bf2f(yl.z)));
        o.w = f2bf(fmaf(bf2f(w4.w), h.w, bf2f(yl.w)));
        *(ushort4*)(yb + off) = o;
        off += H;
    }
}

// ---- scan pass 3 + fused output head (layer 1): elementwise y into 32KB LDS, then head. ----
__global__ __launch_bounds__(256) void scan3f_kernel(
    const unsigned short* __restrict__ ylT, const unsigned short* __restrict__ wT,
    const float* __restrict__ Cc,
    const unsigned short* __restrict__ xb,
    const float* __restrict__ Wout, const float* __restrict__ bout,
    const float* __restrict__ Wskip,
    float* __restrict__ out){
    __shared__ unsigned short ystage[32 * 512];   // 32 KB
    const int tid  = threadIdx.x;
    const int c    = blockIdx.x;            // chunk 0..NC-1
    const int half = tid >> 7;
    const int j4   = (tid & 127) * 4;
    float4 h = *(const float4*)(Cc + (size_t)c * H + j4);
    size_t off = (size_t)(c * CHUNK + half * 16) * H + j4;
    #pragma unroll 8
    for (int i = 0; i < 16; i++){
        ushort4 yl = *(const ushort4*)(ylT + off);
        ushort4 w4 = *(const ushort4*)(wT + off);
        ushort4 o;
        o.x = f2bf(fmaf(bf2f(w4.x), h.x, bf2f(yl.x)));
        o.y = f2bf(fmaf(bf2f(w4.y), h.y, bf2f(yl.y)));
        o.z = f2bf(fmaf(bf2f(w4.z), h.z, bf2f(yl.z)));
        o.w = f2bf(fmaf(bf2f(w4.w), h.w, bf2f(yl.w)));
        *(ushort4*)(&ystage[(half * 16 + i) * 512 + j4]) = o;
        off += H;
    }
    __syncthreads();

    // output head for this block's 32 rows (same per-row dot order as before)
    const int wave = tid >> 6;
    const int lane = tid & 63;
    const float4* W4 = (const float4*)Wout;
    const float4* S4 = (const float4*)Wskip;
    const float b0 = bout[0], b1 = bout[1], b2 = bout[2], b3 = bout[3];
    for (int rr = 0; rr < 8; ++rr){
        const int r = wave * 8 + rr;
        const int t = c * 32 + r;
        float s0 = 0.f, s1 = 0.f, s2 = 0.f, s3 = 0.f;
        #pragma unroll
        for (int k = lane; k < H; k += 64){
            float yv = bf2f(ystage[r * 512 + k]);
            float4 w = W4[k];
            s0 = fmaf(yv, w.x, s0); s1 = fmaf(yv, w.y, s1);
            s2 = fmaf(yv, w.z, s2); s3 = fmaf(yv, w.w, s3);
        }
        #pragma unroll
        for (int k = lane; k < OBS; k += 64){
            float xv = bf2f(xb[(size_t)t * OBS + k]);
            float4 w = S4[k];
            s0 = fmaf(xv, w.x, s0); s1 = fmaf(xv, w.y, s1);
            s2 = fmaf(xv, w.z, s2); s3 = fmaf(xv, w.w, s3);
        }
        #pragma unroll
        for (int o = 32; o > 0; o >>= 1){
            s0 += __shfl_down(s0, o);
            s1 += __shfl_down(s1, o);
            s2 += __shfl_down(s2, o);
            s3 += __shfl_down(s3, o);
        }
        if (lane == 0){
            out[(size_t)t * 4 + 0] = s0 + b0;
            out[(size_t)t * 4 + 1] = s1 + b1;
            out[(size_t)t * 4 + 2] = s2 + b2;
            out[(size_t)t * 4 + 3] = s3 + b3;
        }
    }
}

extern "C" void kernel_launch(void* const* d_in, const int* in_sizes, int n_in,
                              void* d_out, int out_size, void* d_ws, size_t ws_size,
                              hipStream_t stream)
{
    const float* x     = (const float*)d_in[0];
    const float* W_in0 = (const float*)d_in[1];
    const float* W_B0  = (const float*)d_in[2];
    const float* W_C0  = (const float*)d_in[3];
    const float* W_d0  = (const float*)d_in[4];
    const float* A0    = (const float*)d_in[5];
    const float* W_in1 = (const float*)d_in[6];
    const float* W_B1  = (const float*)d_in[7];
    const float* W_C1  = (const float*)d_in[8];
    const float* W_d1  = (const float*)d_in[9];
    const float* A1    = (const float*)d_in[10];
    const float* Wout  = (const float*)d_in[11];
    const float* bout  = (const float*)d_in[12];
    const float* Wskip = (const float*)d_in[13];
    float* out = (float*)d_out;

    char* ws = (char*)d_ws;
    size_t off = 0;
    auto alloc = [&](size_t bytes) -> void* {
        void* p = ws + off;
        off += (bytes + 255) & ~(size_t)255;
        return p;
    };
    unsigned short* xb  = (unsigned short*)alloc((size_t)T_SIZE * OBS * 2);
    unsigned short* yb  = (unsigned short*)alloc((size_t)T_SIZE * H * 2);  // layer0 y
    unsigned short* Wt0 = (unsigned short*)alloc((size_t)4 * H * OBS * 2);
    unsigned short* Wt1 = (unsigned short*)alloc((size_t)4 * H * H * 2);
    unsigned short* ylT = (unsigned short*)alloc((size_t)T_SIZE * H * 2);
    unsigned short* wT  = (unsigned short*)alloc((size_t)T_SIZE * H * 2);
    float* Pbuf = (float*)alloc((size_t)NC * H * 4);
    float* Hbuf = (float*)alloc((size_t)NC * H * 4);
    float* Pexc = (float*)alloc((size_t)NC * H * 4);
    float* Hexc = (float*)alloc((size_t)NC * H * 4);
    float* Cc   = (float*)alloc((size_t)NC * H * 4);
    float* Pg   = (float*)alloc((size_t)NGRP * H * 4);
    float* Hg   = (float*)alloc((size_t)NGRP * H * 4);
    (void)ws_size; (void)in_sizes; (void)n_in; (void)out_size;

    // ---- merged precision casts / weight transposes (1 dispatch) ----
    prep_kernel<<<14336, 256, 0, stream>>>(x, xb,
                                           W_in0, W_B0, W_C0, W_d0, Wt0,
                                           W_in1, W_B1, W_C1, W_d1, Wt1);

    dim3 ggrid(16, 256);                 // flat-swizzled inside the kernel

    // ---- layer 0 ----
    gemm_layer_kernel<OBS><<<ggrid, 256, 0, stream>>>(xb, Wt0, A0, ylT, wT, Pbuf, Hbuf);
    scan2a_kernel<<<NGRP, 128, 0, stream>>>(Pbuf, Hbuf, Pg, Hg, Pexc, Hexc);
    scan2b_kernel<<<NGRP, 128, 0, stream>>>(Pg, Hg, Pexc, Hexc, Cc);
    scan3_kernel<<<NC, 256, 0, stream>>>(ylT, wT, Cc, yb);

    // ---- layer 1 (output head fused into scan3f; y1 never materialized) ----
    gemm_layer_kernel<H><<<ggrid, 256, 0, stream>>>(yb, Wt1, A1, ylT, wT, Pbuf, Hbuf);
    scan2a_kernel<<<NGRP, 128, 0, stream>>>(Pbuf, Hbuf, Pg, Hg, Pexc, Hexc);
    scan2b_kernel<<<NGRP, 128, 0, stream>>>(Pg, Hg, Pexc, Hexc, Cc);
    scan3f_kernel<<<NC, 256, 0, stream>>>(ylT, wT, Cc,
                                          xb, Wout, bout, Wskip, out);
}

// Round 15
// 297.242 us; speedup vs baseline: 1.0983x; 1.0983x over previous
//
#include <hip/hip_runtime.h>

typedef __attribute__((ext_vector_type(8))) short short8;
typedef __attribute__((ext_vector_type(4))) float floatx4;

#define T_SIZE 32768
#define OBS    256
#define H      512
#define NC     1024    // scan chunks
#define CHUNK  32      // T_SIZE / NC
#define NGRP   64      // scan2 groups
#define GCH    16      // chunks per group

__device__ __forceinline__ unsigned short f2bf(float f){
    union { float f; unsigned u; } v; v.f = f;
    unsigned u = v.u;
    u += 0x7FFFu + ((u >> 16) & 1u);   // round-to-nearest-even
    return (unsigned short)(u >> 16);
}
__device__ __forceinline__ float bf2f(unsigned short u){
    union { unsigned u; float f; } v; v.u = ((unsigned)u) << 16; return v.f;
}

// async global->LDS, 16B per lane; lds base must be wave-uniform (HW adds lane*16)
#define GLOAD_LDS16(g, l) \
    __builtin_amdgcn_global_load_lds((const __attribute__((address_space(1))) unsigned*)(g), \
                                     (__attribute__((address_space(3))) unsigned*)(l), 16, 0, 0)

// ---- merged prep: cast x -> bf16 (blocks 0..8191), tcast W0 set (8192..10239, K=256),
// ----              tcast W1 set (10240..14335, K=512). K innermost: coalesced writes.
__global__ void prep_kernel(const float* __restrict__ x, unsigned short* __restrict__ xb,
                            const float* __restrict__ A0W0, const float* __restrict__ A0W1,
                            const float* __restrict__ A0W2, const float* __restrict__ A0W3,
                            unsigned short* __restrict__ Wt0,
                            const float* __restrict__ A1W0, const float* __restrict__ A1W1,
                            const float* __restrict__ A1W2, const float* __restrict__ A1W3,
                            unsigned short* __restrict__ Wt1){
    const int b = blockIdx.x;
    const int tid = threadIdx.x;
    if (b < 8192){
        int i = b * 256 + tid;                       // n4 = 2097152 = 8192*256 exactly
        float4 v = ((const float4*)x)[i];
        ushort4 o;
        o.x = f2bf(v.x); o.y = f2bf(v.y); o.z = f2bf(v.z); o.w = f2bf(v.w);
        ((ushort4*)xb)[i] = o;
    } else if (b < 10240){
        const int K = OBS, KH = OBS * H;
        int idx = (b - 8192) * 256 + tid;            // 4*KH = 524288 = 2048*256 exactly
        int s   = idx / KH;
        int rem = idx - s * KH;
        int h = rem >> 8;            // K = 256: k innermost
        int k = rem & 255;
        const float* W = (s == 0) ? A0W0 : (s == 1) ? A0W1 : (s == 2) ? A0W2 : A0W3;
        int bb = h >> 4, hh = h & 15;
        Wt0[(size_t)((bb * 4 + s) * 16 + hh) * K + k] = f2bf(W[(size_t)k * H + h]);
    } else {
        const int K = H, KH = H * H;
        int idx = (b - 10240) * 256 + tid;           // 4*KH = 1048576 = 4096*256 exactly
        int s   = idx / KH;
        int rem = idx - s * KH;
        int h = rem >> 9;            // K = 512: k innermost
        int k = rem & 511;
        const float* W = (s == 0) ? A1W0 : (s == 1) ? A1W1 : (s == 2) ? A1W2 : A1W3;
        int bb = h >> 4, hh = h & 15;
        Wt1[(size_t)((bb * 4 + s) * 16 + hh) * K + k] = f2bf(W[(size_t)k * H + h]);
    }
}

// ---- fused 4-matrix GEMM (ring-3 LDS pipeline) + IN-EPILOGUE LOCAL SCAN ----
// Outputs yl = C*h_local and w = C*prefix (bf16, [T][512]); downstream scan is
// pure elementwise y = yl + w*h_in. Chunk aggregates (Pbuf/Hbuf) as before.
template<int K>
__global__ __launch_bounds__(256, 3) void gemm_layer_kernel(
    const unsigned short* __restrict__ xb,
    const unsigned short* __restrict__ wt,
    const float* __restrict__ A_log,
    unsigned short* __restrict__ ylT, unsigned short* __restrict__ wT,
    float* __restrict__ Pbuf, float* __restrict__ Hbuf)
{
    __shared__ unsigned short SM[3][8192];   // 48 KB

    const int tid  = threadIdx.x;
    const int wave = tid >> 6;
    const int lane = tid & 63;
    const int ml   = lane & 15;
    const int quad = lane >> 4;
    const int wm   = wave & 1;
    const int wn   = wave >> 1;

    const int flat = blockIdx.y * 16 + blockIdx.x;
    const int xcd  = flat & 7;
    const int j    = flat >> 3;
    const int nb   = j & 15;                 // 0..15 : h block of 32
    const int mb   = (j >> 4) * 8 + xcd;     // 0..255 : t tile of 128
    const int m0   = mb * 128;

    const int srow = tid >> 2;
    const int sel  = (((tid & 3) ^ ((tid >> 3) & 3))) * 8;   // staging XOR swizzle
    const int swz  = (ml >> 1) & 3;                          // read-side XOR swizzle

    const unsigned short* pa0 = xb + (size_t)(m0 + srow) * K + sel;
    const unsigned short* pa1 = pa0 + (size_t)64 * K;
    const unsigned short* pb0 = wt + (size_t)(nb * 128 + srow) * K + sel;
    const unsigned short* pb1 = pb0 + (size_t)64 * K;

    const int ldsA0 = (wave * 64 + 0  ) * 8;
    const int ldsA1 = (wave * 64 + 256) * 8;

    const int rbaseA = (wm * 64 + ml) * 32 + (quad ^ swz) * 8;
    const int rbaseB = (wn * 64 + ml) * 32 + (quad ^ swz) * 8;

    floatx4 acc[4][4];
    #pragma unroll
    for (int i = 0; i < 4; i++)
        #pragma unroll
        for (int jj = 0; jj < 4; jj++)
            acc[i][jj] = (floatx4)(0.0f);

    constexpr int NK = K >> 5;   // 8 or 16

#define STAGE(kt_) { const int b_ = (kt_) % 3; const int ko_ = (kt_) * 32; \
        GLOAD_LDS16(pa0 + ko_, &SM[b_][ldsA0]); \
        GLOAD_LDS16(pa1 + ko_, &SM[b_][ldsA1]); \
        GLOAD_LDS16(pb0 + ko_, &SM[b_][4096 + ldsA0]); \
        GLOAD_LDS16(pb1 + ko_, &SM[b_][4096 + ldsA1]); }

    // prologue: stage K-tiles 0,1 (depth-2 prefetch); wait tile 0 only
    STAGE(0); STAGE(1);
    asm volatile("s_waitcnt vmcnt(4)" ::: "memory");
    __builtin_amdgcn_s_barrier();
    __builtin_amdgcn_sched_barrier(0);

    #pragma unroll
    for (int kk = 0; kk < NK; ++kk){
        const int cur = kk % 3;

        if (kk + 2 < NK) STAGE(kk + 2);   // into slot of tile kk-1 (reads done, barrier passed)

        short8 av[4], bv[4];
        #pragma unroll
        for (int i = 0; i < 4; i++)
            av[i] = *(const short8*)(&SM[cur][0] + rbaseA + i * 16 * 32);
        #pragma unroll
        for (int jj = 0; jj < 4; jj++)
            bv[jj] = *(const short8*)(&SM[cur][4096] + rbaseB + jj * 16 * 32);

        __builtin_amdgcn_s_setprio(1);
        #pragma unroll
        for (int i = 0; i < 4; i++)
            #pragma unroll
            for (int jj = 0; jj < 4; jj++)
                acc[i][jj] = __builtin_amdgcn_mfma_f32_16x16x32_bf16(av[i], bv[jj], acc[i][jj], 0, 0, 0);
        __builtin_amdgcn_s_setprio(0);

        if (kk + 1 < NK){
            if (kk + 2 < NK) { asm volatile("s_waitcnt vmcnt(4)" ::: "memory"); }
            else             { asm volatile("s_waitcnt vmcnt(0)" ::: "memory"); }
            __builtin_amdgcn_s_barrier();
            __builtin_amdgcn_sched_barrier(0);
        }
    }
    __syncthreads();   // full drain before epilogue reuses SM

#undef STAGE

    // ---- epilogue pass 1: per-element a/bx/C in regs (fp32); segment aggregates -> segbuf ----
    unsigned short* SMe = &SM[0][0];
    float2* segbuf = (float2*)(SMe + 12288);  // [ch 4][seg 8][col 32] float2 = 8 KB
    const int col = wn * 16 + ml;             // 0..31 h within block
    const int h   = nb * 32 + col;
    const float Aneg = -expf(A_log[h]);

    float va[4][4], vb[4][4], vc[4][4];
    #pragma unroll
    for (int i = 0; i < 4; i++){
        float p = 1.0f, hh = 0.0f;
        #pragma unroll
        for (int r = 0; r < 4; r++){
            float dv = acc[i][3][r];
            float delta = 1.0f / (1.0f + __expf(-dv));
            float a  = __expf(delta * Aneg);
            float bx = acc[i][1][r] * acc[i][0][r];
            va[i][r] = a; vb[i][r] = bx; vc[i][r] = acc[i][2][r];
            hh = fmaf(a, hh, bx);
            p *= a;
        }
        const int ch = wm * 2 + (i >> 1);
        const int s  = (i & 1) * 4 + quad;
        segbuf[(ch * 8 + s) * 32 + col] = make_float2(p, hh);
    }
    __syncthreads();

    // ---- epilogue pass 2: exclusive segment fold; per-element yl=C*h_local, w=C*prefix ----
    #pragma unroll
    for (int i = 0; i < 4; i++){
        const int ch = wm * 2 + (i >> 1);
        const int s  = (i & 1) * 4 + quad;
        float Pexc = 1.0f, Hexc = 0.0f;
        for (int sp = 0; sp < s; sp++){   // <=7 LDS reads, divergent-bounded
            float2 ph = segbuf[(ch * 8 + sp) * 32 + col];
            Hexc = fmaf(ph.x, Hexc, ph.y);
            Pexc *= ph.x;
        }
        float hcur = Hexc, pf = Pexc;
        #pragma unroll
        for (int r = 0; r < 4; r++){
            hcur = fmaf(va[i][r], hcur, vb[i][r]);
            pf  *= va[i][r];
            int trow = wm * 64 + i * 16 + quad * 4 + r;   // C/D: row = quad*4 + reg
            SMe[        trow * 32 + col] = f2bf(vc[i][r] * hcur);
            SMe[4096 +  trow * 32 + col] = f2bf(vc[i][r] * pf);
        }
    }
    if (tid < 128){
        const int ccol = tid & 31, ch = tid >> 5;
        float P = 1.0f, Hc = 0.0f;
        #pragma unroll
        for (int s = 0; s < 8; s++){
            float2 ph = segbuf[(ch * 8 + s) * 32 + ccol];
            Hc = fmaf(ph.x, Hc, ph.y);
            P *= ph.x;
        }
        const int c = mb * 4 + ch;
        Pbuf[(size_t)c * H + nb * 32 + ccol] = P;
        Hbuf[(size_t)c * H + nb * 32 + ccol] = Hc;
    }
    __syncthreads();
    {
        // store yl/w to [T][512]: unit u (16B) -> row u>>2 (0..127), col-part u&3 (8 shorts)
        const short8* s8 = (const short8*)SMe;
        #pragma unroll
        for (int arr = 0; arr < 2; arr++){
            unsigned short* bp = (arr == 0) ? ylT : wT;
            #pragma unroll
            for (int half = 0; half < 2; half++){
                int u = half * 256 + tid;
                int row = u >> 2, part = u & 3;
                *(short8*)(bp + (size_t)(m0 + row) * H + nb * 32 + part * 8) = s8[arr * 512 + u];
            }
        }
    }
}

// ---- scan pass 2a: 64 groups x 16 chunks -> group aggregates only ----
__global__ void scan2a_kernel(const float* __restrict__ P, const float* __restrict__ Hc,
                              float* __restrict__ Pg, float* __restrict__ Hg){
    const int g  = blockIdx.x;          // 0..63
    const int j4 = threadIdx.x * 4;     // 128 threads
    float4 pc = {1.f,1.f,1.f,1.f}, hc = {0.f,0.f,0.f,0.f};
    #pragma unroll
    for (int i = 0; i < GCH; i++){
        size_t o = (size_t)(g * GCH + i) * H + j4;
        float4 P4 = *(const float4*)(P + o);
        float4 H4 = *(const float4*)(Hc + o);
        hc.x = fmaf(P4.x, hc.x, H4.x); pc.x *= P4.x;
        hc.y = fmaf(P4.y, hc.y, H4.y); pc.y *= P4.y;
        hc.z = fmaf(P4.z, hc.z, H4.z); pc.z *= P4.z;
        hc.w = fmaf(P4.w, hc.w, H4.w); pc.w *= P4.w;
    }
    *(float4*)(Pg + (size_t)g * H + j4) = pc;
    *(float4*)(Hg + (size_t)g * H + j4) = hc;
}

// ---- scan pass 2b: sequential exclusive combine over 64 groups (1 block, 512 threads).
// ---- Same fold order as the previous inline loop -> bit-identical h_in. ----
__global__ void scan2b_kernel(const float* __restrict__ Pg, const float* __restrict__ Hg,
                              float* __restrict__ Cg){
    const int j = threadIdx.x;
    float carry = 0.0f;
    for (int g0 = 0; g0 < NGRP; g0 += 8){
        float p[8], h[8];
        #pragma unroll
        for (int i = 0; i < 8; i++){
            p[i] = Pg[(size_t)(g0 + i) * H + j];
            h[i] = Hg[(size_t)(g0 + i) * H + j];
        }
        #pragma unroll
        for (int i = 0; i < 8; i++){
            Cg[(size_t)(g0 + i) * H + j] = carry;
            carry = fmaf(p[i], carry, h[i]);
        }
    }
}

// ---- scan pass 3 (ELEMENTWISE): h_in = Cg[grp] + <=15 chunk folds; y = yl + w*h_in. ----
__global__ __launch_bounds__(256) void scan3_kernel(
    const unsigned short* __restrict__ ylT, const unsigned short* __restrict__ wT,
    const float* __restrict__ P, const float* __restrict__ Hc,
    const float* __restrict__ Cg,
    unsigned short* __restrict__ yb){
    const int c    = blockIdx.x;            // chunk 0..NC-1 (wave-uniform)
    const int half = threadIdx.x >> 7;      // rows 0-15 / 16-31 (independent)
    const int j4   = (threadIdx.x & 127) * 4;
    const int grp  = c >> 4;                // GCH = 16
    float4 h = *(const float4*)(Cg + (size_t)grp * H + j4);
    for (int cc = grp << 4; cc < c; ++cc){  // <=15 L2-hot folds
        float4 P4 = *(const float4*)(P + (size_t)cc * H + j4);
        float4 H4 = *(const float4*)(Hc + (size_t)cc * H + j4);
        h.x = fmaf(P4.x, h.x, H4.x);
        h.y = fmaf(P4.y, h.y, H4.y);
        h.z = fmaf(P4.z, h.z, H4.z);
        h.w = fmaf(P4.w, h.w, H4.w);
    }
    size_t off = (size_t)(c * CHUNK + half * 16) * H + j4;
    #pragma unroll 8
    for (int i = 0; i < 16; i++){
        ushort4 yl = *(const ushort4*)(ylT + off);
        ushort4 w4 = *(const ushort4*)(wT + off);
        ushort4 o;
        o.x = f2bf(fmaf(bf2f(w4.x), h.x, bf2f(yl.x)));
        o.y = f2bf(fmaf(bf2f(w4.y), h.y, bf2f(yl.y)));
        o.z = f2bf(fmaf(bf2f(w4.z), h.z, bf2f(yl.z)));
        o.w = f2bf(fmaf(bf2f(w4.w), h.w, bf2f(yl.w)));
        *(ushort4*)(yb + off) = o;
        off += H;
    }
}

// ---- scan pass 3 + fused output head (layer 1): elementwise y into 32KB LDS, then head. ----
__global__ __launch_bounds__(256) void scan3f_kernel(
    const unsigned short* __restrict__ ylT, const unsigned short* __restrict__ wT,
    const float* __restrict__ P, const float* __restrict__ Hc,
    const float* __restrict__ Cg,
    const unsigned short* __restrict__ xb,
    const float* __restrict__ Wout, const float* __restrict__ bout,
    const float* __restrict__ Wskip,
    float* __restrict__ out){
    __shared__ unsigned short ystage[32 * 512];   // 32 KB
    const int tid  = threadIdx.x;
    const int c    = blockIdx.x;            // chunk 0..NC-1
    const int half = tid >> 7;
    const int j4   = (tid & 127) * 4;
    const int grp  = c >> 4;
    float4 h = *(const float4*)(Cg + (size_t)grp * H + j4);
    for (int cc = grp << 4; cc < c; ++cc){
        float4 P4 = *(const float4*)(P + (size_t)cc * H + j4);
        float4 H4 = *(const float4*)(Hc + (size_t)cc * H + j4);
        h.x = fmaf(P4.x, h.x, H4.x);
        h.y = fmaf(P4.y, h.y, H4.y);
        h.z = fmaf(P4.z, h.z, H4.z);
        h.w = fmaf(P4.w, h.w, H4.w);
    }
    size_t off = (size_t)(c * CHUNK + half * 16) * H + j4;
    #pragma unroll 8
    for (int i = 0; i < 16; i++){
        ushort4 yl = *(const ushort4*)(ylT + off);
        ushort4 w4 = *(const ushort4*)(wT + off);
        ushort4 o;
        o.x = f2bf(fmaf(bf2f(w4.x), h.x, bf2f(yl.x)));
        o.y = f2bf(fmaf(bf2f(w4.y), h.y, bf2f(yl.y)));
        o.z = f2bf(fmaf(bf2f(w4.z), h.z, bf2f(yl.z)));
        o.w = f2bf(fmaf(bf2f(w4.w), h.w, bf2f(yl.w)));
        *(ushort4*)(&ystage[(half * 16 + i) * 512 + j4]) = o;
        off += H;
    }
    __syncthreads();

    // output head for this block's 32 rows (same per-row dot order as before)
    const int wave = tid >> 6;
    const int lane = tid & 63;
    const float4* W4 = (const float4*)Wout;
    const float4* S4 = (const float4*)Wskip;
    const float b0 = bout[0], b1 = bout[1], b2 = bout[2], b3 = bout[3];
    for (int rr = 0; rr < 8; ++rr){
        const int r = wave * 8 + rr;
        const int t = c * 32 + r;
        float s0 = 0.f, s1 = 0.f, s2 = 0.f, s3 = 0.f;
        #pragma unroll
        for (int k = lane; k < H; k += 64){
            float yv = bf2f(ystage[r * 512 + k]);
            float4 w = W4[k];
            s0 = fmaf(yv, w.x, s0); s1 = fmaf(yv, w.y, s1);
            s2 = fmaf(yv, w.z, s2); s3 = fmaf(yv, w.w, s3);
        }
        #pragma unroll
        for (int k = lane; k < OBS; k += 64){
            float xv = bf2f(xb[(size_t)t * OBS + k]);
            float4 w = S4[k];
            s0 = fmaf(xv, w.x, s0); s1 = fmaf(xv, w.y, s1);
            s2 = fmaf(xv, w.z, s2); s3 = fmaf(xv, w.w, s3);
        }
        #pragma unroll
        for (int o = 32; o > 0; o >>= 1){
            s0 += __shfl_down(s0, o);
            s1 += __shfl_down(s1, o);
            s2 += __shfl_down(s2, o);
            s3 += __shfl_down(s3, o);
        }
        if (lane == 0){
            out[(size_t)t * 4 + 0] = s0 + b0;
            out[(size_t)t * 4 + 1] = s1 + b1;
            out[(size_t)t * 4 + 2] = s2 + b2;
            out[(size_t)t * 4 + 3] = s3 + b3;
        }
    }
}

extern "C" void kernel_launch(void* const* d_in, const int* in_sizes, int n_in,
                              void* d_out, int out_size, void* d_ws, size_t ws_size,
                              hipStream_t stream)
{
    const float* x     = (const float*)d_in[0];
    const float* W_in0 = (const float*)d_in[1];
    const float* W_B0  = (const float*)d_in[2];
    const float* W_C0  = (const float*)d_in[3];
    const float* W_d0  = (const float*)d_in[4];
    const float* A0    = (const float*)d_in[5];
    const float* W_in1 = (const float*)d_in[6];
    const float* W_B1  = (const float*)d_in[7];
    const float* W_C1  = (const float*)d_in[8];
    const float* W_d1  = (const float*)d_in[9];
    const float* A1    = (const float*)d_in[10];
    const float* Wout  = (const float*)d_in[11];
    const float* bout  = (const float*)d_in[12];
    const float* Wskip = (const float*)d_in[13];
    float* out = (float*)d_out;

    char* ws = (char*)d_ws;
    size_t off = 0;
    auto alloc = [&](size_t bytes) -> void* {
        void* p = ws + off;
        off += (bytes + 255) & ~(size_t)255;
        return p;
    };
    unsigned short* xb  = (unsigned short*)alloc((size_t)T_SIZE * OBS * 2);
    unsigned short* yb  = (unsigned short*)alloc((size_t)T_SIZE * H * 2);  // layer0 y
    unsigned short* Wt0 = (unsigned short*)alloc((size_t)4 * H * OBS * 2);
    unsigned short* Wt1 = (unsigned short*)alloc((size_t)4 * H * H * 2);
    unsigned short* ylT = (unsigned short*)alloc((size_t)T_SIZE * H * 2);
    unsigned short* wT  = (unsigned short*)alloc((size_t)T_SIZE * H * 2);
    float* Pbuf = (float*)alloc((size_t)NC * H * 4);
    float* Hbuf = (float*)alloc((size_t)NC * H * 4);
    float* Pg   = (float*)alloc((size_t)NGRP * H * 4);
    float* Hg   = (float*)alloc((size_t)NGRP * H * 4);
    float* Cg   = (float*)alloc((size_t)NGRP * H * 4);
    (void)ws_size; (void)in_sizes; (void)n_in; (void)out_size;

    // ---- merged precision casts / weight transposes (1 dispatch) ----
    prep_kernel<<<14336, 256, 0, stream>>>(x, xb,
                                           W_in0, W_B0, W_C0, W_d0, Wt0,
                                           W_in1, W_B1, W_C1, W_d1, Wt1);

    dim3 ggrid(16, 256);                 // flat-swizzled inside the kernel

    // ---- layer 0 ----
    gemm_layer_kernel<OBS><<<ggrid, 256, 0, stream>>>(xb, Wt0, A0, ylT, wT, Pbuf, Hbuf);
    scan2a_kernel<<<NGRP, 128, 0, stream>>>(Pbuf, Hbuf, Pg, Hg);
    scan2b_kernel<<<1, H, 0, stream>>>(Pg, Hg, Cg);
    scan3_kernel<<<NC, 256, 0, stream>>>(ylT, wT, Pbuf, Hbuf, Cg, yb);

    // ---- layer 1 (output head fused into scan3f; y1 never materialized) ----
    gemm_layer_kernel<H><<<ggrid, 256, 0, stream>>>(yb, Wt1, A1, ylT, wT, Pbuf, Hbuf);
    scan2a_kernel<<<NGRP, 128, 0, stream>>>(Pbuf, Hbuf, Pg, Hg);
    scan2b_kernel<<<1, H, 0, stream>>>(Pg, Hg, Cg);
    scan3f_kernel<<<NC, 256, 0, stream>>>(ylT, wT, Pbuf, Hbuf, Cg,
                                          xb, Wout, bout, Wskip, out);
}